// Round 4
// baseline (15.600 us; speedup 1.0000x reference)
//
#include <hip/hip_runtime.h>
#include <math.h>

#define NROWS 100000
#define MCENT 256
#define EENS 10
#define WAVES 8

// NORM_CONST = 1/((2*pi)^2 * sigma^4), sigma=0.1
#define NORM_CONST_F 253.30295910584444f
// -0.5/sigma^2 * log2(e) = -50 * 1.4426950408889634
#define EXP2_SCALE (-72.13475204444817f)

__global__ __launch_bounds__(512) void fused_kernel(
    const float* __restrict__ x,                   // N x 4
    const float* __restrict__ ensemble_probs,      // N x 10
    const float* __restrict__ ensemble_norm_probs, // N x 1
    const float* __restrict__ weights,             // 10
    const float* __restrict__ centers,             // 256 x 4
    const float* __restrict__ coefficients,        // 256
    float* __restrict__ out)                       // [0,N) ensemble, [N,2N) net_out
{
    __shared__ float s_p[WAVES][64];

    const int t = threadIdx.x;
    const int lane = t & 63;
    const int wid = __builtin_amdgcn_readfirstlane(t >> 6);  // wave-uniform SGPR

    const int r = blockIdx.x * 64 + lane;
    const int rc = (r < NROWS) ? r : (NROWS - 1);

    // ---- issue all global loads up front (hide HBM latency under compute) ----
    const float4 xv = ((const float4*)x)[rc];

    float2 pr0, pr1, pr2, pr3, pr4;
    float npv = 0.0f;
    if (wid == 1) {  // wave-uniform branch: wave 1 prefetches its ensemble rows
        const float2* pr = (const float2*)(ensemble_probs + (size_t)rc * EENS);
        pr0 = pr[0]; pr1 = pr[1]; pr2 = pr[2]; pr3 = pr[3]; pr4 = pr[4];
        npv = ensemble_norm_probs[rc];
    }

    // ---- mean of coefficients, computed redundantly by every wave ----
    const float4 cf4 = ((const float4*)coefficients)[lane];
    float s = (cf4.x + cf4.y) + (cf4.z + cf4.w);
    #pragma unroll
    for (int off = 32; off > 0; off >>= 1) s += __shfl_down(s, off, 64);
    const float mean = __builtin_amdgcn_readfirstlane(s) * (1.0f / 256.0f);

    // ---- each wave owns a 32-center chunk (wave-uniform addr -> s_load) ----
    const float4* __restrict__ C = (const float4*)centers + wid * 32;
    const float*  __restrict__ K = coefficients + wid * 32;

    float acc0 = 0.f, acc1 = 0.f;  // two chains for ILP
    #pragma unroll 8
    for (int k = 0; k < 32; k += 2) {
        {
            const float4 c = C[k];
            const float wc = K[k] - mean;
            const float dx = xv.x - c.x, dy = xv.y - c.y,
                        dz = xv.z - c.z, dw = xv.w - c.w;
            float d2 = dx * dx;
            d2 = fmaf(dy, dy, d2);
            d2 = fmaf(dz, dz, d2);
            d2 = fmaf(dw, dw, d2);
            acc0 = fmaf(wc, __builtin_amdgcn_exp2f(d2 * EXP2_SCALE), acc0);
        }
        {
            const float4 c = C[k + 1];
            const float wc = K[k + 1] - mean;
            const float dx = xv.x - c.x, dy = xv.y - c.y,
                        dz = xv.z - c.z, dw = xv.w - c.w;
            float d2 = dx * dx;
            d2 = fmaf(dy, dy, d2);
            d2 = fmaf(dz, dz, d2);
            d2 = fmaf(dw, dw, d2);
            acc1 = fmaf(wc, __builtin_amdgcn_exp2f(d2 * EXP2_SCALE), acc1);
        }
    }

    s_p[wid][lane] = acc0 + acc1;
    __syncthreads();

    if (wid == 0) {
        if (r < NROWS) {
            float P = 0.f;
            #pragma unroll
            for (int w = 0; w < WAVES; ++w) P += s_p[w][lane];
            out[NROWS + r] = P * NORM_CONST_F;
        }
    } else if (wid == 1) {
        if (r < NROWS) {
            float wv[EENS];
            float wsum = 0.0f;
            #pragma unroll
            for (int e = 0; e < EENS; ++e) { wv[e] = weights[e]; wsum += wv[e]; }
            float ens = npv * (1.0f - wsum);
            ens = fmaf(pr0.x, wv[0], ens);
            ens = fmaf(pr0.y, wv[1], ens);
            ens = fmaf(pr1.x, wv[2], ens);
            ens = fmaf(pr1.y, wv[3], ens);
            ens = fmaf(pr2.x, wv[4], ens);
            ens = fmaf(pr2.y, wv[5], ens);
            ens = fmaf(pr3.x, wv[6], ens);
            ens = fmaf(pr3.y, wv[7], ens);
            ens = fmaf(pr4.x, wv[8], ens);
            ens = fmaf(pr4.y, wv[9], ens);
            out[r] = ens;
        }
    }
}

extern "C" void kernel_launch(void* const* d_in, const int* in_sizes, int n_in,
                              void* d_out, int out_size, void* d_ws, size_t ws_size,
                              hipStream_t stream) {
    const float* x       = (const float*)d_in[0];
    const float* eprobs  = (const float*)d_in[1];
    const float* enorm   = (const float*)d_in[2];
    const float* weights = (const float*)d_in[3];
    const float* centers = (const float*)d_in[4];
    const float* coeffs  = (const float*)d_in[5];
    float* out = (float*)d_out;

    const int blocks = (NROWS + 63) / 64;  // 1563 blocks x 8 waves
    fused_kernel<<<blocks, 512, 0, stream>>>(
        x, eprobs, enorm, weights, centers, coeffs, out);
}